// Round 1
// baseline (204.113 us; speedup 1.0000x reference)
//
#include <hip/hip_runtime.h>
#include <math.h>
#include <float.h>

#define BS 32
#define NQ 300
#define NC 2001
#define NT 25

// ---------------- Kernel 1: cost^T[b][t][q] = -softmax(logits[b,q,:])[targets[b,t]] ----------------
__global__ __launch_bounds__(64) void cost_kernel(const float* __restrict__ logits,
                                                  const int* __restrict__ targets,
                                                  float* __restrict__ costT) {
    int row = blockIdx.x;            // b*NQ + q
    int b = row / NQ;
    int q = row - b * NQ;
    const float* lp = logits + (size_t)row * NC;
    int lane = threadIdx.x;

    // max over NC
    float m = -FLT_MAX;
    for (int c = lane; c < NC; c += 64) m = fmaxf(m, lp[c]);
    for (int off = 1; off < 64; off <<= 1) m = fmaxf(m, __shfl_xor(m, off));

    // sum of exp
    float s = 0.f;
    for (int c = lane; c < NC; c += 64) s += expf(lp[c] - m);
    for (int off = 1; off < 64; off <<= 1) s += __shfl_xor(s, off);

    if (lane < NT) {
        int t = targets[b * NT + lane];
        float p = expf(lp[t] - m) / s;
        costT[((size_t)b * NT + lane) * NQ + q] = -p;
    }
}

// ---------------- Kernel 2: Jonker-Volgenant LSAP per batch (rows=targets 25, cols=queries 300) ----
__global__ __launch_bounds__(64) void lsap_kernel(const float* __restrict__ costT,
                                                  int* __restrict__ out) {
    int b = blockIdx.x;
    int tid = threadIdx.x;

    __shared__ float   C[NT * NQ];      // 30000 B
    __shared__ double  shortest[NQ];    // 2400 B
    __shared__ double  v[NQ];           // 2400 B
    __shared__ double  u[NT];           // 200 B
    __shared__ int     path[NQ];
    __shared__ int     SC[NQ];
    __shared__ int     row4col[NQ];
    __shared__ int     col4row[NT];
    __shared__ int     sr_rows[NT];

    const float* src = costT + (size_t)b * NT * NQ;
    for (int k = tid; k < NT * NQ; k += 64) C[k] = src[k];
    for (int j = tid; j < NQ; j += 64) { v[j] = 0.0; row4col[j] = -1; }
    if (tid < NT) { u[tid] = 0.0; col4row[tid] = -1; }
    __syncthreads();

    for (int cur = 0; cur < NT; ++cur) {
        for (int j = tid; j < NQ; j += 64) { shortest[j] = INFINITY; path[j] = -1; SC[j] = 0; }
        __syncthreads();

        double minVal = 0.0;   // wave-uniform
        int i = cur;           // wave-uniform
        int nsr = 0;
        int sink = -1;

        while (sink == -1) {
            if (tid == 0) sr_rows[nsr] = i;
            nsr++;
            double ui = u[i];  // uniform LDS read (u stable inside this loop)

            // relax + local argmin over owned columns (ascending j => lowest-index tie-break)
            double lmin = INFINITY;
            int    lidx = 0x7fffffff;
            for (int j = tid; j < NQ; j += 64) {
                if (!SC[j]) {
                    double d = ((minVal + (double)C[i * NQ + j]) - ui) - v[j];
                    if (d < shortest[j]) { shortest[j] = d; path[j] = i; }
                    double sj = shortest[j];
                    if (sj < lmin) { lmin = sj; lidx = j; }
                }
            }
            // butterfly min-reduce, tie-break lowest column index (matches np.argmin first-min)
            for (int off = 1; off < 64; off <<= 1) {
                double om = __shfl_xor(lmin, off);
                int    oi = __shfl_xor(lidx, off);
                if (om < lmin || (om == lmin && oi < lidx)) { lmin = om; lidx = oi; }
            }
            minVal = lmin;
            int jpos = lidx;
            if (tid == 0) SC[jpos] = 1;
            int r = row4col[jpos];   // uniform read; row4col not written in this loop
            if (r == -1) sink = jpos; else i = r;
            __syncthreads();         // make SC[jpos] (and shortest/path) visible for next iter / epilogue
        }

        // dual updates (rows in sr_rows are distinct; sr_rows[0] == cur)
        if (tid == 0) {
            u[cur] += minVal;
        } else if (tid < nsr) {
            int irow = sr_rows[tid];
            u[irow] += minVal - shortest[col4row[irow]];
        }
        for (int j = tid; j < NQ; j += 64) {
            if (SC[j]) v[j] -= minVal - shortest[j];
        }
        __syncthreads();

        // augment along path (serial, <= NT steps)
        if (tid == 0) {
            int j = sink;
            while (true) {
                int ii = path[j];
                row4col[j] = ii;
                int nj = col4row[ii];
                col4row[ii] = j;
                j = nj;
                if (ii == cur) break;
            }
        }
        __syncthreads();
    }

    // epilogue: order = stable argsort(col4row); values distinct -> rank = #smaller
    if (tid < NT) {
        int myq = col4row[tid];
        int rank = 0;
        for (int k = 0; k < NT; ++k) {
            if (col4row[k] < myq) rank++;
        }
        out[b * NT + rank]           = myq;  // row_inds
        out[BS * NT + b * NT + rank] = tid;  // col_inds
    }
}

extern "C" void kernel_launch(void* const* d_in, const int* in_sizes, int n_in,
                              void* d_out, int out_size, void* d_ws, size_t ws_size,
                              hipStream_t stream) {
    const float* logits  = (const float*)d_in[0];
    const int*   targets = (const int*)d_in[1];
    int*         out     = (int*)d_out;
    float*       costT   = (float*)d_ws;   // BS*NT*NQ floats = 960000 B

    cost_kernel<<<BS * NQ, 64, 0, stream>>>(logits, targets, costT);
    lsap_kernel<<<BS, 64, 0, stream>>>(costT, out);
}

// Round 2
// 164.765 us; speedup vs baseline: 1.2388x; 1.2388x over previous
//
#include <hip/hip_runtime.h>
#include <math.h>
#include <float.h>

#define BS 32
#define NQ 300
#define NC 2001
#define NT 25
#define KSLOT 5   // ceil(NQ/64)

// ---------------- Kernel 1: cost^T[b][t][q] = -softmax(logits[b,q,:])[targets[b,t]] ----------------
__global__ __launch_bounds__(64) void cost_kernel(const float* __restrict__ logits,
                                                  const int* __restrict__ targets,
                                                  float* __restrict__ costT) {
    int row = blockIdx.x;            // b*NQ + q
    int b = row / NQ;
    int q = row - b * NQ;
    const float* lp = logits + (size_t)row * NC;
    int lane = threadIdx.x;

    // alignment: row base elem offset = row*NC; (row*2001) % 4 == row % 4
    int head = (4 - (row & 3)) & 3;                  // scalar elems before 16B boundary
    int nvec = (NC - head) >> 2;                     // float4 count
    int tail = (NC - head) & 3;                      // scalar elems after vectors
    const float4* vp = (const float4*)(lp + head);

    // ---- pass 1: max ----
    float m = -FLT_MAX;
    for (int k = lane; k < nvec; k += 64) {
        float4 x = vp[k];
        m = fmaxf(m, fmaxf(fmaxf(x.x, x.y), fmaxf(x.z, x.w)));
    }
    if (lane < head) m = fmaxf(m, lp[lane]);
    if (lane < tail) m = fmaxf(m, lp[head + 4 * nvec + lane]);
    for (int off = 1; off < 64; off <<= 1) m = fmaxf(m, __shfl_xor(m, off));

    // ---- pass 2: sum of exp ----
    float s = 0.f;
    for (int k = lane; k < nvec; k += 64) {
        float4 x = vp[k];
        s += expf(x.x - m) + expf(x.y - m) + expf(x.z - m) + expf(x.w - m);
    }
    if (lane < head) s += expf(lp[lane] - m);
    if (lane < tail) s += expf(lp[head + 4 * nvec + lane] - m);
    for (int off = 1; off < 64; off <<= 1) s += __shfl_xor(s, off);

    if (lane < NT) {
        int t = targets[b * NT + lane];
        float p = expf(lp[t] - m) / s;
        costT[((size_t)b * NT + lane) * NQ + q] = -p;
    }
}

// ---------------- Kernel 2: Jonker-Volgenant LSAP per batch (rows=targets 25, cols=queries 300) ----
// Dijkstra state (shortest, v, path, SC) is register-resident: lane owns columns j = lane + 64k.
__global__ __launch_bounds__(64) void lsap_kernel(const float* __restrict__ costT,
                                                  int* __restrict__ out) {
    int b = blockIdx.x;
    int tid = threadIdx.x;

    __shared__ float   C[NT * NQ];       // 30000 B
    __shared__ double  u[NT];
    __shared__ double  shortestS[NQ];    // published at scan time (for dual update)
    __shared__ int     pathS[NQ];        // published at scan time (for augment)
    __shared__ int     row4col[NQ];
    __shared__ int     col4row[NT];
    __shared__ int     sr_rows[NT];

    // vectorized C load: 7500 floats, batch base 30000 B -> 16B aligned
    {
        const float4* src4 = (const float4*)(costT + (size_t)b * NT * NQ);
        float4* dst4 = (float4*)C;
        for (int k = tid; k < (NT * NQ) / 4; k += 64) dst4[k] = src4[k];
    }
    for (int j = tid; j < NQ; j += 64) row4col[j] = -1;
    if (tid < NT) { u[tid] = 0.0; col4row[tid] = -1; }

    double v_r[KSLOT];
    bool   own[KSLOT];
    #pragma unroll
    for (int k = 0; k < KSLOT; ++k) { v_r[k] = 0.0; own[k] = (tid + 64 * k) < NQ; }
    __syncthreads();

    for (int cur = 0; cur < NT; ++cur) {
        double shortest_r[KSLOT];
        int    path_r[KSLOT];
        bool   sc_r[KSLOT];
        #pragma unroll
        for (int k = 0; k < KSLOT; ++k) { shortest_r[k] = INFINITY; path_r[k] = -1; sc_r[k] = false; }

        double minVal = 0.0;   // wave-uniform
        int i = cur;           // wave-uniform
        int nsr = 0;
        int sink = -1;

        while (sink == -1) {
            if (tid == 0) sr_rows[nsr] = i;
            nsr++;
            double ui = u[i];  // uniform LDS read (u stable during Dijkstra)

            // relax owned, unscanned columns + local min (registers only; C from LDS)
            double lmin = INFINITY;
            #pragma unroll
            for (int k = 0; k < KSLOT; ++k) {
                if (own[k] && !sc_r[k]) {
                    int j = tid + 64 * k;
                    double d = ((minVal + (double)C[i * NQ + j]) - ui) - v_r[k];
                    if (d < shortest_r[k]) { shortest_r[k] = d; path_r[k] = i; }
                    if (shortest_r[k] < lmin) lmin = shortest_r[k];
                }
            }
            // value-only f64 min butterfly
            double gmin = lmin;
            #pragma unroll
            for (int off = 1; off < 64; off <<= 1) {
                double o = __shfl_xor(gmin, off);
                if (o < gmin) gmin = o;
            }
            // lowest-column argmin via ballots (exact equality vs gmin; k-major = ascending j)
            int jpos = -1;
            #pragma unroll
            for (int k = 0; k < KSLOT; ++k) {
                unsigned long long mk =
                    __ballot(own[k] && !sc_r[k] && shortest_r[k] == gmin);
                if (jpos < 0 && mk) jpos = 64 * k + __builtin_ctzll(mk);
            }
            minVal = gmin;

            // mark scanned; publish path/shortest for the epilogue phases
            int kj = jpos >> 6, lj = jpos & 63;
            if (tid == lj) {
                sc_r[kj] = true;
                pathS[jpos] = path_r[kj];
            }
            if (tid == 0) shortestS[jpos] = gmin;

            int r = row4col[jpos];   // uniform read; stable during Dijkstra
            if (r == -1) sink = jpos; else i = r;
            __syncthreads();         // publish pathS/shortestS/sr_rows
        }

        // dual updates (rows in sr_rows are distinct; sr_rows[0] == cur)
        if (tid == 0) {
            u[cur] += minVal;
        } else if (tid < nsr) {
            int irow = sr_rows[tid];
            u[irow] += minVal - shortestS[col4row[irow]];
        }
        #pragma unroll
        for (int k = 0; k < KSLOT; ++k) {
            if (sc_r[k]) v_r[k] -= minVal - shortest_r[k];
        }
        __syncthreads();   // duals (col4row reads) done before augment rewrites col4row

        // augment along path (serial, <= NT steps)
        if (tid == 0) {
            int j = sink;
            while (true) {
                int ii = pathS[j];
                row4col[j] = ii;
                int nj = col4row[ii];
                col4row[ii] = j;
                j = nj;
                if (ii == cur) break;
            }
        }
        __syncthreads();
    }

    // epilogue: order = stable argsort(col4row); values distinct -> rank = #smaller
    if (tid < NT) {
        int myq = col4row[tid];
        int rank = 0;
        for (int k = 0; k < NT; ++k) {
            if (col4row[k] < myq) rank++;
        }
        out[b * NT + rank]           = myq;  // row_inds
        out[BS * NT + b * NT + rank] = tid;  // col_inds
    }
}

extern "C" void kernel_launch(void* const* d_in, const int* in_sizes, int n_in,
                              void* d_out, int out_size, void* d_ws, size_t ws_size,
                              hipStream_t stream) {
    const float* logits  = (const float*)d_in[0];
    const int*   targets = (const int*)d_in[1];
    int*         out     = (int*)d_out;
    float*       costT   = (float*)d_ws;   // BS*NT*NQ floats = 960000 B

    cost_kernel<<<BS * NQ, 64, 0, stream>>>(logits, targets, costT);
    lsap_kernel<<<BS, 64, 0, stream>>>(costT, out);
}